// Round 1
// baseline (228.039 us; speedup 1.0000x reference)
//
#include <hip/hip_runtime.h>
#include <hip/hip_bf16.h>
#include <math.h>

// Problem constants (fixed by the reference)
#define NSEG 32
#define T_DIM 8
#define F_DIM 32
#define P_DIM 8
#define TF 256           // T_DIM * F_DIM
#define OUT_PER_SEG 2048 // T*P*F
#define EPS_DENOM 1e-16f

#define K1_THREADS 1024
#define CHUNK 128

// Tiny MLP: h = elu(pos @ W1 + b1) @ W2 + b2  (per node, P=8 outputs)
__device__ __forceinline__ void compute_h(
    float h[P_DIM], const float* __restrict__ pos, int n,
    const float* __restrict__ W1, const float* __restrict__ b1,
    const float* __restrict__ W2, const float* __restrict__ b2) {
  float p0 = pos[3 * n + 0];
  float p1 = pos[3 * n + 1];
  float p2 = pos[3 * n + 2];
  float a[P_DIM];
#pragma unroll
  for (int p = 0; p < P_DIM; p++) {
    float v = b1[p] + p0 * W1[0 * P_DIM + p] + p1 * W1[1 * P_DIM + p] + p2 * W1[2 * P_DIM + p];
    a[p] = v > 0.f ? v : (__expf(v) - 1.f);  // ELU, alpha=1
  }
#pragma unroll
  for (int p = 0; p < P_DIM; p++) {
    float v = b2[p];
#pragma unroll
    for (int j = 0; j < P_DIM; j++) v += a[j] * W2[j * P_DIM + p];
    h[p] = v;
  }
}

// Kernel 1: one block per segment. Two passes (max, then sum of exp) over the
// segment's contiguous node range (seg is sorted -> binary search bounds).
// Writes ms[b*16 + p] = max, ms[b*16 + 8 + p] = sum.
__global__ __launch_bounds__(K1_THREADS) void stats_kernel(
    const float* __restrict__ pos, const int* __restrict__ seg,
    const float* __restrict__ W1, const float* __restrict__ b1,
    const float* __restrict__ W2, const float* __restrict__ b2,
    float* __restrict__ ms, int N) {
  int b = blockIdx.x;
  __shared__ int bounds[2];
  if (threadIdx.x < 2) {
    int target = b + (int)threadIdx.x;
    int lo = 0, hi = N;
    while (lo < hi) {
      int mid = (lo + hi) >> 1;
      if (seg[mid] < target) lo = mid + 1; else hi = mid;
    }
    bounds[threadIdx.x] = lo;
  }
  __syncthreads();
  int start = bounds[0], end = bounds[1];
  int tid = threadIdx.x;

  // Pass 1: local max
  float lmax[P_DIM];
#pragma unroll
  for (int p = 0; p < P_DIM; p++) lmax[p] = -INFINITY;
  for (int i = start + tid; i < end; i += K1_THREADS) {
    float h[P_DIM];
    compute_h(h, pos, i, W1, b1, W2, b2);
#pragma unroll
    for (int p = 0; p < P_DIM; p++) lmax[p] = fmaxf(lmax[p], h[p]);
  }
#pragma unroll
  for (int off = 32; off >= 1; off >>= 1)
#pragma unroll
    for (int p = 0; p < P_DIM; p++)
      lmax[p] = fmaxf(lmax[p], __shfl_down(lmax[p], off, 64));

  __shared__ float wred[P_DIM][K1_THREADS / 64];
  __shared__ float msh[P_DIM];
  int wid = tid >> 6, lane = tid & 63;
  if (lane == 0) {
#pragma unroll
    for (int p = 0; p < P_DIM; p++) wred[p][wid] = lmax[p];
  }
  __syncthreads();
  if (tid < P_DIM) {
    float mm = -INFINITY;
#pragma unroll
    for (int w = 0; w < K1_THREADS / 64; w++) mm = fmaxf(mm, wred[tid][w]);
    msh[tid] = mm;
  }
  __syncthreads();
  float m[P_DIM];
#pragma unroll
  for (int p = 0; p < P_DIM; p++) m[p] = msh[p];

  // Pass 2: local sum of exp(h - m)
  float lsum[P_DIM];
#pragma unroll
  for (int p = 0; p < P_DIM; p++) lsum[p] = 0.f;
  for (int i = start + tid; i < end; i += K1_THREADS) {
    float h[P_DIM];
    compute_h(h, pos, i, W1, b1, W2, b2);
#pragma unroll
    for (int p = 0; p < P_DIM; p++) lsum[p] += __expf(h[p] - m[p]);
  }
#pragma unroll
  for (int off = 32; off >= 1; off >>= 1)
#pragma unroll
    for (int p = 0; p < P_DIM; p++)
      lsum[p] += __shfl_down(lsum[p], off, 64);
  __syncthreads();  // ensure previous wred reads are done
  if (lane == 0) {
#pragma unroll
    for (int p = 0; p < P_DIM; p++) wred[p][wid] = lsum[p];
  }
  __syncthreads();
  if (tid < P_DIM) {
    float ss = 0.f;
#pragma unroll
    for (int w = 0; w < K1_THREADS / 64; w++) ss += wred[tid][w];
    ms[b * 16 + tid] = msh[tid];
    ms[b * 16 + 8 + tid] = ss;
  }
}

__device__ __forceinline__ void flush_acc(float* __restrict__ out, int sg, int tid,
                                          float acc[P_DIM]) {
  int t = tid >> 5, f = tid & 31;
  int bo = sg * OUT_PER_SEG + t * (P_DIM * F_DIM) + f;
#pragma unroll
  for (int p = 0; p < P_DIM; p++) {
    unsafeAtomicAdd(&out[bo + p * F_DIM], acc[p]);
    acc[p] = 0.f;
  }
}

// Kernel 2: each block owns CHUNK consecutive nodes.
// Phase A: first CHUNK threads compute softmax weight w[node][p] into LDS.
// Phase B: thread = (t,f); stream x coalesced, FMA into 8 regs (one per p),
// flush to out via f32 atomics on segment change / at end.
__global__ __launch_bounds__(256) void accum_kernel(
    const float* __restrict__ x, const float* __restrict__ pos,
    const int* __restrict__ seg, const float* __restrict__ ms,
    const float* __restrict__ W1, const float* __restrict__ b1,
    const float* __restrict__ W2, const float* __restrict__ b2,
    float* __restrict__ out, int N) {
  __shared__ __align__(16) float wbuf[CHUNK][P_DIM];
  __shared__ int sbuf[CHUNK];

  int base = blockIdx.x * CHUNK;
  int cnt = N - base;
  if (cnt > CHUNK) cnt = CHUNK;
  int tid = threadIdx.x;

  if (tid < cnt) {
    int n = base + tid;
    int sg = seg[n];
    sbuf[tid] = sg;
    float h[P_DIM];
    compute_h(h, pos, n, W1, b1, W2, b2);
#pragma unroll
    for (int p = 0; p < P_DIM; p++) {
      float mm = ms[sg * 16 + p];
      float ss = ms[sg * 16 + 8 + p];
      wbuf[tid][p] = __expf(h[p] - mm) / (ss + EPS_DENOM);
    }
  }
  __syncthreads();

  const float* xp = x + (size_t)base * TF + tid;
  float acc[P_DIM];
#pragma unroll
  for (int p = 0; p < P_DIM; p++) acc[p] = 0.f;

  int cur = sbuf[0];
  int last = sbuf[cnt - 1];

  if (cur == last) {
    // Fast path: single segment in this chunk. Unroll 8 for loads in flight.
    int i = 0;
    for (; i + 8 <= cnt; i += 8) {
      float xv[8];
#pragma unroll
      for (int j = 0; j < 8; j++) xv[j] = xp[(size_t)(i + j) * TF];
#pragma unroll
      for (int j = 0; j < 8; j++) {
        const float4* wrow = (const float4*)&wbuf[i + j][0];
        float4 wa = wrow[0];
        float4 wb = wrow[1];
        acc[0] += xv[j] * wa.x;
        acc[1] += xv[j] * wa.y;
        acc[2] += xv[j] * wa.z;
        acc[3] += xv[j] * wa.w;
        acc[4] += xv[j] * wb.x;
        acc[5] += xv[j] * wb.y;
        acc[6] += xv[j] * wb.z;
        acc[7] += xv[j] * wb.w;
      }
    }
    for (; i < cnt; i++) {
      float xv = xp[(size_t)i * TF];
      const float4* wrow = (const float4*)&wbuf[i][0];
      float4 wa = wrow[0];
      float4 wb = wrow[1];
      acc[0] += xv * wa.x; acc[1] += xv * wa.y;
      acc[2] += xv * wa.z; acc[3] += xv * wa.w;
      acc[4] += xv * wb.x; acc[5] += xv * wb.y;
      acc[6] += xv * wb.z; acc[7] += xv * wb.w;
    }
    flush_acc(out, cur, tid, acc);
  } else {
    // Slow path: chunk spans a segment boundary (rare; seg is sorted).
    for (int i = 0; i < cnt; i++) {
      int sgi = sbuf[i];
      if (sgi != cur) {
        flush_acc(out, cur, tid, acc);
        cur = sgi;
      }
      float xv = xp[(size_t)i * TF];
      const float4* wrow = (const float4*)&wbuf[i][0];
      float4 wa = wrow[0];
      float4 wb = wrow[1];
      acc[0] += xv * wa.x; acc[1] += xv * wa.y;
      acc[2] += xv * wa.z; acc[3] += xv * wa.w;
      acc[4] += xv * wb.x; acc[5] += xv * wb.y;
      acc[6] += xv * wb.z; acc[7] += xv * wb.w;
    }
    flush_acc(out, cur, tid, acc);
  }
}

extern "C" void kernel_launch(void* const* d_in, const int* in_sizes, int n_in,
                              void* d_out, int out_size, void* d_ws, size_t ws_size,
                              hipStream_t stream) {
  const float* pos = (const float*)d_in[0];
  const float* x   = (const float*)d_in[1];
  const int*   seg = (const int*)d_in[2];
  const float* W1  = (const float*)d_in[3];
  const float* b1  = (const float*)d_in[4];
  const float* W2  = (const float*)d_in[5];
  const float* b2  = (const float*)d_in[6];
  float* out = (float*)d_out;
  float* ms  = (float*)d_ws;  // [NSEG][16]: max (8) then sum (8)
  int N = in_sizes[2];

  hipMemsetAsync(d_out, 0, (size_t)out_size * sizeof(float), stream);

  stats_kernel<<<NSEG, K1_THREADS, 0, stream>>>(pos, seg, W1, b1, W2, b2, ms, N);

  int nblk = (N + CHUNK - 1) / CHUNK;
  accum_kernel<<<nblk, 256, 0, stream>>>(x, pos, seg, ms, W1, b1, W2, b2, out, N);
}